// Round 10
// baseline (10126.894 us; speedup 1.0000x reference)
//
#include <hip/hip_runtime.h>
#include <stdint.h>

// GRU: L=2, D=H=1024, S=512, B=32.
// Phase 1: xg[s,l,gate,b,h] = x[s,b,:] @ W[l,gate,h,:]^T  (bf16 MFMA GEMM)
// Phase 2: persistent recurrence, 256 WGs x 128 threads (2 waves). Each WG
//   owns a 16-row g-slice x 16 b-cols; waves split K (512 each) and reduce
//   via LDS. U-slices LDS-resident (96 KB). Cross-WG exchange: tagged u64
//   lines {u32 epoch | 2 bf16}, producer fire-and-forget (no vmcnt, no
//   flags). Consumer: narrow sentinel poll (1 tagged line per lane = 64
//   producers), single-shot 32x dwordx4 stage, in-register exact-tag verify
//   with selective reload. Epoch chain makes single-buffering race-free:
//   h(s+1) is published only after this WG consumed rh(s) from ALL
//   producers, and each producer published rh(s) only after it fully
//   consumed h(s) — so no line is overwritten while any consumer needs it.

typedef __attribute__((ext_vector_type(8))) short bf16x8;
typedef __attribute__((ext_vector_type(4))) float f32x4;
typedef __attribute__((ext_vector_type(4))) unsigned int u32x4;

#define NL 2
#define SB 32
#define HD 1024
#define SEQ 512

// ---- workspace layout (bytes) ----
#define XG_ELEMS   ((size_t)SEQ*6*SB*HD)
#define XG_OFF     0ull
#define XBF_OFF    (XG_OFF + XG_ELEMS*2)
#define XBF_ELEMS  ((size_t)SEQ*SB*HD)
#define WBF_OFF    (XBF_OFF + XBF_ELEMS*2)
#define WBF_ELEMS  ((size_t)6*HD*HD)
#define HLN_OFF    (WBF_OFF + WBF_ELEMS*2)     // tagged h lines [64 brow][512] u64
#define LN_U64S    ((size_t)NL*SB*512)         // 32768 u64 per buffer
#define RLN_OFF    (HLN_OFF + LN_U64S*8)       // tagged r*h lines
#define WS_NEED    (RLN_OFF + LN_U64S*8)

__device__ __forceinline__ unsigned short f2bf(float f) {
  unsigned int u = __float_as_uint(f);
  u = u + 0x7fffu + ((u >> 16) & 1u);
  return (unsigned short)(u >> 16);
}
__device__ __forceinline__ float bf2f(unsigned int bits) {
  return __uint_as_float(bits << 16);
}
__device__ __forceinline__ f32x4 unpack4(uint2 u) {
  f32x4 v;
  v[0] = bf2f(u.x & 0xffffu); v[1] = bf2f(u.x >> 16);
  v[2] = bf2f(u.y & 0xffffu); v[3] = bf2f(u.y >> 16);
  return v;
}

__device__ __forceinline__ void st_wt(unsigned long long* p, unsigned long long v) {
  __hip_atomic_store(p, v, __ATOMIC_RELAXED, __HIP_MEMORY_SCOPE_AGENT);
}
__device__ __forceinline__ unsigned ld_tag(const unsigned* p) {
  return __hip_atomic_load(p, __ATOMIC_RELAXED, __HIP_MEMORY_SCOPE_AGENT);
}

// ---------------- fp32 -> bf16 convert ----------------
__global__ void cvt_f32_bf16(const float* __restrict__ src,
                             unsigned short* __restrict__ dst, int n4) {
  int i = blockIdx.x * blockDim.x + threadIdx.x;
  int st = gridDim.x * blockDim.x;
  for (; i < n4; i += st) {
    float4 v = ((const float4*)src)[i];
    ushort4 o = { f2bf(v.x), f2bf(v.y), f2bf(v.z), f2bf(v.w) };
    ((ushort4*)dst)[i] = o;
  }
}

// ---------------- phase 1 GEMM ----------------
__global__ __launch_bounds__(256) void gemm_xg(const unsigned short* __restrict__ Wb,
                                               const unsigned short* __restrict__ xb,
                                               unsigned short* __restrict__ xg) {
  __shared__ short As[128 * 32];
  __shared__ short Bs[128 * 32];
  const int lg = blockIdx.z;
  const int m0 = blockIdx.y * 128;
  const int n0 = blockIdx.x * 128;
  const int tid = threadIdx.x, w = tid >> 6, lane = tid & 63;
  const int wm = (w >> 1) * 64, wn = (w & 1) * 64;
  const unsigned short* Ag = Wb + (size_t)lg * HD * HD;

  f32x4 acc[4][4] = {};

  for (int k0 = 0; k0 < HD; k0 += 32) {
    __syncthreads();
#pragma unroll
    for (int i = 0; i < 2; i++) {
      int off = (i * 256 + tid) * 16;
      int rr = off >> 6;
      int cc = (off >> 4) & 3;
      *(uint4*)((char*)As + off) = *(const uint4*)(Ag + (size_t)(m0 + rr) * HD + k0 + cc * 8);
      *(uint4*)((char*)Bs + off) = *(const uint4*)(xb + (size_t)(n0 + rr) * HD + k0 + cc * 8);
    }
    __syncthreads();
    bf16x8 af[4], bf[4];
#pragma unroll
    for (int mi = 0; mi < 4; mi++)
      af[mi] = *(const bf16x8*)&As[(wm + mi * 16 + (lane & 15)) * 32 + ((lane >> 4) << 3)];
#pragma unroll
    for (int ni = 0; ni < 4; ni++)
      bf[ni] = *(const bf16x8*)&Bs[(wn + ni * 16 + (lane & 15)) * 32 + ((lane >> 4) << 3)];
#pragma unroll
    for (int mi = 0; mi < 4; mi++)
#pragma unroll
      for (int ni = 0; ni < 4; ni++)
        acc[mi][ni] = __builtin_amdgcn_mfma_f32_16x16x32_bf16(af[mi], bf[ni], acc[mi][ni], 0, 0, 0);
  }

#pragma unroll
  for (int mi = 0; mi < 4; mi++) {
    int g = m0 + wm + mi * 16 + ((lane >> 4) << 2);
#pragma unroll
    for (int ni = 0; ni < 4; ni++) {
      int n = n0 + wn + ni * 16 + (lane & 15);
      int s = n >> 5, b = n & 31;
      ushort4 o = { f2bf(acc[mi][ni][0]), f2bf(acc[mi][ni][1]),
                    f2bf(acc[mi][ni][2]), f2bf(acc[mi][ni][3]) };
      *(ushort4*)(xg + ((size_t)(s * 6 + lg)) * (SB * HD) + (size_t)b * HD + g) = o;
    }
  }
}

// ---------------- phase 2: recurrence ----------------
// A-frag from swizzled LDS weights: row = lane&15, k = k0 + (lane>>4)*8
__device__ __forceinline__ bf16x8 afrag(const short* wlds, int gate, int lane, int k) {
  int r = lane & 15;
  int kk = k + ((lane >> 4) << 3);
  int ck = (kk >> 3) ^ (r & 7);
  return *(const bf16x8*)&wlds[gate * 16384 + r * HD + (ck << 3)];
}

// producer: 2 tagged lines (4 values), fire-and-forget (tag travels with data)
__device__ __forceinline__ void publish2(unsigned long long* dst, const f32x4 vals,
                                         unsigned tag) {
  unsigned lo0 = (unsigned)f2bf(vals[0]) | ((unsigned)f2bf(vals[1]) << 16);
  unsigned lo1 = (unsigned)f2bf(vals[2]) | ((unsigned)f2bf(vals[3]) << 16);
  st_wt(dst,     ((unsigned long long)tag << 32) | lo0);
  st_wt(dst + 1, ((unsigned long long)tag << 32) | lo1);
}

// narrow sentinel: lane i polls the tag word of producer i's first line
__device__ __forceinline__ void sent_wait(const unsigned* tagptr, unsigned tag) {
  bool ok;
  do { ok = (ld_tag(tagptr) >= tag); } while (!__all(ok));
}

// single-shot stage of this wave's K-half: 32 x dwordx4 (tagged u64 pairs)
__device__ __forceinline__ void stage_tagged(const unsigned long long* base, u32x4* vv) {
#pragma unroll
  for (int kk = 0; kk < 16; kk++) {
    asm volatile("global_load_dwordx4 %0, %1, off sc0 sc1"
                 : "=v"(vv[2 * kk])     : "v"(base + kk * 16)     : "memory");
    asm volatile("global_load_dwordx4 %0, %1, off sc0 sc1"
                 : "=v"(vv[2 * kk + 1]) : "v"(base + kk * 16 + 2) : "memory");
  }
  asm volatile("s_waitcnt vmcnt(0)" ::: "memory");
  __builtin_amdgcn_sched_barrier(0);
}

// exact-tag verify; reload only stale 16B chunks (expected ~zero iterations)
__device__ __forceinline__ void verify32(u32x4* vv, unsigned tag,
                                         const unsigned long long* base) {
  for (;;) {
    bool ok = true;
#pragma unroll
    for (int i = 0; i < 32; i++) ok &= (vv[i][1] == tag) & (vv[i][3] == tag);
    if (__all(ok)) return;
#pragma unroll
    for (int kk = 0; kk < 16; kk++) {
      if (vv[2 * kk][1] != tag || vv[2 * kk][3] != tag)
        asm volatile("global_load_dwordx4 %0, %1, off sc0 sc1"
                     : "=v"(vv[2 * kk]) : "v"(base + kk * 16) : "memory");
      if (vv[2 * kk + 1][1] != tag || vv[2 * kk + 1][3] != tag)
        asm volatile("global_load_dwordx4 %0, %1, off sc0 sc1"
                     : "=v"(vv[2 * kk + 1]) : "v"(base + kk * 16 + 2) : "memory");
    }
    asm volatile("s_waitcnt vmcnt(0)" ::: "memory");
    __builtin_amdgcn_sched_barrier(0);
  }
}

__device__ __forceinline__ bf16x8 repack(const u32x4 a, const u32x4 b) {
  union { u32x4 w; bf16x8 v; } u;
  u.w[0] = a[0]; u.w[1] = a[2]; u.w[2] = b[0]; u.w[3] = b[2];
  return u.v;
}

__global__ __launch_bounds__(128, 1) void gru_rec(
    const float* __restrict__ h0,
    const float* __restrict__ Uz, const float* __restrict__ Ur, const float* __restrict__ Uh,
    const float* __restrict__ bz, const float* __restrict__ br, const float* __restrict__ bh,
    const unsigned short* __restrict__ xg,
    unsigned long long* __restrict__ hln,
    unsigned long long* __restrict__ rln,
    float* __restrict__ out) {
  __shared__ short wlds[3 * 16 * HD];     // 96 KB bf16 U-slices (1 WG/CU)
  __shared__ f32x4 redz[2][64];           // per-wave K-half partials
  __shared__ f32x4 redr[2][64];
  __shared__ f32x4 redh[2][64];

  const int wg = blockIdx.x;              // 256 WGs x 2 waves
  const int l = wg >> 7;
  const int gs = wg & 63;
  const int g0 = gs * 16;
  const int b0 = ((wg >> 6) & 1) * 16;
  const int tid = threadIdx.x;
  const int w = tid >> 6;                 // K-half owner
  const int lane = tid & 63;
  const int col = lane & 15;
  const int sub = lane >> 4;
  const int rb = sub << 2;

  // ---- load U slices into LDS (bf16, XOR-swizzled 8-elem chunks) ----
  const float* Us[3] = { Uz, Ur, Uh };
#pragma unroll
  for (int gate = 0; gate < 3; gate++) {
    const float* U = Us[gate] + (size_t)l * HD * HD + (size_t)g0 * HD;
    for (int it = 0; it < 16; it++) {
      int chunk = it * 128 + tid;         // 2048 chunks of 8 elems
      int r = chunk >> 7;
      int ck = chunk & 127;
      const float* src = U + (size_t)r * HD + ck * 8;
      float4 a = *(const float4*)src;
      float4 bq = *(const float4*)(src + 4);
      bf16x8 o;
      o[0] = (short)f2bf(a.x); o[1] = (short)f2bf(a.y);
      o[2] = (short)f2bf(a.z); o[3] = (short)f2bf(a.w);
      o[4] = (short)f2bf(bq.x); o[5] = (short)f2bf(bq.y);
      o[6] = (short)f2bf(bq.z); o[7] = (short)f2bf(bq.w);
      int sck = ck ^ (r & 7);
      *(bf16x8*)&wlds[gate * 16384 + r * HD + sck * 8] = o;
    }
  }
  __syncthreads();                        // wlds complete (both waves)

  f32x4 vbz = *(const f32x4*)(bz + l * HD + g0 + rb);
  f32x4 vbr = *(const f32x4*)(br + l * HD + g0 + rb);
  f32x4 vbh = *(const f32x4*)(bh + l * HD + g0 + rb);

  const int brow = l * SB + b0 + col;
  f32x4 hreg = *(const f32x4*)(h0 + (size_t)brow * HD + g0 + rb);

  unsigned long long* hrow = hln + (size_t)brow * 512;
  unsigned long long* rrow = rln + (size_t)brow * 512;
  unsigned long long* hdst = hrow + 8 * gs + 2 * sub;     // this lane's 2 lines
  unsigned long long* rdst = rrow + 8 * gs + 2 * sub;
  const unsigned long long* hb = hrow + w * 256 + sub * 4;  // stage base (K-half)
  const unsigned long long* rp = rrow + w * 256 + sub * 4;
  const unsigned* hsent = (const unsigned*)(hrow + 8 * lane) + 1;  // producer lane's tag
  const unsigned* rsent = (const unsigned*)(rrow + 8 * lane) + 1;

  if (w == 0) publish2(hdst, hreg, 1u);

  // xg current-step values, prefetched one step ahead (wave 0 only)
  size_t xb0 = ((size_t)l * 3) * (SB * HD) + (size_t)(b0 + col) * HD + g0 + rb;
  uint2 xzc = {}, xrc = {}, xhc = {};
  if (w == 0) {
    xzc = *(const uint2*)(xg + xb0);
    xrc = *(const uint2*)(xg + xb0 + SB * HD);
    xhc = *(const uint2*)(xg + xb0 + 2 * SB * HD);
  }
  uint2 xzn = {}, xrn = {}, xhn = {};

  u32x4 vv[32];
  f32x4 z = { 0, 0, 0, 0 };

  for (int s = 0; s < SEQ; s++) {
    const unsigned tag = (unsigned)(s + 1);

    // ---- phase A: z, r (this wave's K-half) ----
    sent_wait(hsent, tag);
    stage_tagged(hb, vv);
    verify32(vv, tag, hb);
    f32x4 az = { 0, 0, 0, 0 }, ar = { 0, 0, 0, 0 };
#pragma unroll
    for (int kk = 0; kk < 16; kk++) {
      bf16x8 bfr = repack(vv[2 * kk], vv[2 * kk + 1]);
      int k = w * 512 + kk * 32;
      az = __builtin_amdgcn_mfma_f32_16x16x32_bf16(afrag(wlds, 0, lane, k), bfr, az, 0, 0, 0);
      ar = __builtin_amdgcn_mfma_f32_16x16x32_bf16(afrag(wlds, 1, lane, k), bfr, ar, 0, 0, 0);
    }
    redz[w][lane] = az;
    redr[w][lane] = ar;
    __syncthreads();                      // partials ready

    if (w == 0) {
      f32x4 sz = redz[0][lane] + redz[1][lane];
      f32x4 sr = redr[0][lane] + redr[1][lane];
      f32x4 xzf = unpack4(xzc), xrf = unpack4(xrc);
      f32x4 rh;
#pragma unroll
      for (int j = 0; j < 4; j++) {
        float za = xzf[j] + vbz[j] + sz[j];
        float ra = xrf[j] + vbr[j] + sr[j];
        z[j] = 1.f / (1.f + __expf(-za));
        rh[j] = (1.f / (1.f + __expf(-ra))) * hreg[j];
      }
      publish2(rdst, rh, tag);
      // prefetch next step's xg (overlaps phase-B exchange latency)
      int sn = (s + 1 < SEQ) ? s + 1 : s;
      size_t xbn = ((size_t)sn * 6 + l * 3) * (SB * HD) + (size_t)(b0 + col) * HD + g0 + rb;
      xzn = *(const uint2*)(xg + xbn);
      xrn = *(const uint2*)(xg + xbn + SB * HD);
      xhn = *(const uint2*)(xg + xbn + 2 * SB * HD);
    }

    // ---- phase B: hh, h update ----
    sent_wait(rsent, tag);
    stage_tagged(rp, vv);
    verify32(vv, tag, rp);
    f32x4 ah = { 0, 0, 0, 0 };
#pragma unroll
    for (int kk = 0; kk < 16; kk++) {
      bf16x8 bfr = repack(vv[2 * kk], vv[2 * kk + 1]);
      int k = w * 512 + kk * 32;
      ah = __builtin_amdgcn_mfma_f32_16x16x32_bf16(afrag(wlds, 2, lane, k), bfr, ah, 0, 0, 0);
    }
    redh[w][lane] = ah;
    __syncthreads();                      // partials ready

    if (w == 0) {
      f32x4 sh = redh[0][lane] + redh[1][lane];
      f32x4 xhf = unpack4(xhc);
#pragma unroll
      for (int j = 0; j < 4; j++) {
        float ha = xhf[j] + vbh[j] + sh[j];
        float e = __expf(2.f * ha);                     // tanh via exp
        float hh = 1.f - 2.f / (e + 1.f);
        hreg[j] = (1.f - z[j]) * hreg[j] + z[j] * hh;
      }
      publish2(hdst, hreg, tag + 1);
      if (l == 1)   // output stream is LAST layer only
        *(f32x4*)(out + (size_t)s * (SB * HD) + (size_t)(b0 + col) * HD + g0 + rb) = hreg;
      if (s == SEQ - 1)
        *(f32x4*)(out + (size_t)SEQ * SB * HD + (size_t)brow * HD + g0 + rb) = hreg;
      xzc = xzn; xrc = xrn; xhc = xhn;
    }
  }
}

extern "C" void kernel_launch(void* const* d_in, const int* in_sizes, int n_in,
                              void* d_out, int out_size, void* d_ws, size_t ws_size,
                              hipStream_t stream) {
  const float* x  = (const float*)d_in[0];
  const float* h0 = (const float*)d_in[1];
  const float* Wz = (const float*)d_in[2];
  const float* Wr = (const float*)d_in[3];
  const float* Wh = (const float*)d_in[4];
  const float* Uz = (const float*)d_in[5];
  const float* Ur = (const float*)d_in[6];
  const float* Uh = (const float*)d_in[7];
  const float* bz = (const float*)d_in[8];
  const float* br = (const float*)d_in[9];
  const float* bh = (const float*)d_in[10];

  char* ws = (char*)d_ws;
  unsigned short* xg  = (unsigned short*)(ws + XG_OFF);
  unsigned short* xbf = (unsigned short*)(ws + XBF_OFF);
  unsigned short* wbf = (unsigned short*)(ws + WBF_OFF);

  // clear epoch tags (replay safety): hln + rln contiguous
  hipMemsetAsync(ws + HLN_OFF, 0, LN_U64S * 16, stream);

  cvt_f32_bf16<<<1024, 256, 0, stream>>>(x, xbf, (int)(XBF_ELEMS / 4));
  const float* Wsrc[3] = { Wz, Wr, Wh };
  for (int gate = 0; gate < 3; gate++)
    for (int l = 0; l < 2; l++)
      cvt_f32_bf16<<<512, 256, 0, stream>>>(Wsrc[gate] + (size_t)l * HD * HD,
                                            wbf + ((size_t)(l * 3 + gate)) * HD * HD,
                                            HD * HD / 4);

  gemm_xg<<<dim3(128, 8, 6), 256, 0, stream>>>(wbf, xbf, xg);

  gru_rec<<<256, 128, 0, stream>>>(h0, Uz, Ur, Uh, bz, br, bh, xg,
                                   (unsigned long long*)(ws + HLN_OFF),
                                   (unsigned long long*)(ws + RLN_OFF),
                                   (float*)d_out);
}

// Round 11
// 4617.562 us; speedup vs baseline: 2.1931x; 2.1931x over previous
//
#include <hip/hip_runtime.h>
#include <stdint.h>

// GRU: L=2, D=H=1024, S=512, B=32.
// Phase 1: xg[s,l,gate,b,h] = x[s,b,:] @ W[l,gate,h,:]^T  (bf16 MFMA GEMM)
// Phase 2: persistent recurrence, 256 single-wave WGs (16x16 (g,b) tile,
//   full K=1024 per wave). U-slices LDS-resident (96 KB). Cross-WG
//   exchange = R8 protocol (best known good): untagged bf16 data stores,
//   s_waitcnt vmcnt(0) release, per-producer flag; consumer polls 64 flags
//   (1/lane) then bulk-loads payload with wide plain LLC loads (sc0 sc1).
//   R11 change: 8x PAYLOAD+FLAG REPLICATION — producers write 8 copies,
//   consumer gs&7 reads its replica. Cuts per-line consumer fan-out 64->8
//   to test/relieve LLC hot-line serialization. All replicas drained by the
//   same vmcnt(0) before any flag store => same release semantics as R8.

typedef __attribute__((ext_vector_type(8))) short bf16x8;
typedef __attribute__((ext_vector_type(4))) float f32x4;
typedef __attribute__((ext_vector_type(4))) unsigned int u32x4;

#define NL 2
#define SB 32
#define HD 1024
#define SEQ 512
#define NREP 8

// ---- workspace layout (bytes) ----
#define XG_ELEMS   ((size_t)SEQ*6*SB*HD)
#define XG_OFF     0ull
#define XBF_OFF    (XG_OFF + XG_ELEMS*2)
#define XBF_ELEMS  ((size_t)SEQ*SB*HD)
#define WBF_OFF    (XBF_OFF + XBF_ELEMS*2)
#define WBF_ELEMS  ((size_t)6*HD*HD)
#define REP_U64S   ((size_t)NL*SB*256)          // 16384 u64 per replica
#define HBUF_OFF   (WBF_OFF + WBF_ELEMS*2)      // [NREP][64 brow][256 u64]
#define RBUF_OFF   (HBUF_OFF + REP_U64S*NREP*8)
#define FLG_WORDS_REP (4*64*16)                 // per replica: grp x prod x 16
#define HFLG_OFF   (RBUF_OFF + REP_U64S*NREP*8) // [NREP][4][64][16] u32
#define RFLG_OFF   (HFLG_OFF + (size_t)FLG_WORDS_REP*NREP*4)
#define FLG_BYTES  ((size_t)FLG_WORDS_REP*NREP*4)
#define WS_NEED    (RFLG_OFF + FLG_BYTES)

__device__ __forceinline__ unsigned short f2bf(float f) {
  unsigned int u = __float_as_uint(f);
  u = u + 0x7fffu + ((u >> 16) & 1u);
  return (unsigned short)(u >> 16);
}
__device__ __forceinline__ float bf2f(unsigned int bits) {
  return __uint_as_float(bits << 16);
}
__device__ __forceinline__ f32x4 unpack4(uint2 u) {
  f32x4 v;
  v[0] = bf2f(u.x & 0xffffu); v[1] = bf2f(u.x >> 16);
  v[2] = bf2f(u.y & 0xffffu); v[3] = bf2f(u.y >> 16);
  return v;
}

__device__ __forceinline__ void st_wt(unsigned long long* p, unsigned long long v) {
  __hip_atomic_store(p, v, __ATOMIC_RELAXED, __HIP_MEMORY_SCOPE_AGENT);
}
__device__ __forceinline__ unsigned ld_flag(const unsigned* p) {
  return __hip_atomic_load(p, __ATOMIC_RELAXED, __HIP_MEMORY_SCOPE_AGENT);
}
__device__ __forceinline__ void st_flag(unsigned* p, unsigned v) {
  __hip_atomic_store(p, v, __ATOMIC_RELAXED, __HIP_MEMORY_SCOPE_AGENT);
}

// ---------------- fp32 -> bf16 convert ----------------
__global__ void cvt_f32_bf16(const float* __restrict__ src,
                             unsigned short* __restrict__ dst, int n4) {
  int i = blockIdx.x * blockDim.x + threadIdx.x;
  int st = gridDim.x * blockDim.x;
  for (; i < n4; i += st) {
    float4 v = ((const float4*)src)[i];
    ushort4 o = { f2bf(v.x), f2bf(v.y), f2bf(v.z), f2bf(v.w) };
    ((ushort4*)dst)[i] = o;
  }
}

// ---------------- phase 1 GEMM ----------------
__global__ __launch_bounds__(256) void gemm_xg(const unsigned short* __restrict__ Wb,
                                               const unsigned short* __restrict__ xb,
                                               unsigned short* __restrict__ xg) {
  __shared__ short As[128 * 32];
  __shared__ short Bs[128 * 32];
  const int lg = blockIdx.z;
  const int m0 = blockIdx.y * 128;
  const int n0 = blockIdx.x * 128;
  const int tid = threadIdx.x, w = tid >> 6, lane = tid & 63;
  const int wm = (w >> 1) * 64, wn = (w & 1) * 64;
  const unsigned short* Ag = Wb + (size_t)lg * HD * HD;

  f32x4 acc[4][4] = {};

  for (int k0 = 0; k0 < HD; k0 += 32) {
    __syncthreads();
#pragma unroll
    for (int i = 0; i < 2; i++) {
      int off = (i * 256 + tid) * 16;
      int rr = off >> 6;
      int cc = (off >> 4) & 3;
      *(uint4*)((char*)As + off) = *(const uint4*)(Ag + (size_t)(m0 + rr) * HD + k0 + cc * 8);
      *(uint4*)((char*)Bs + off) = *(const uint4*)(xb + (size_t)(n0 + rr) * HD + k0 + cc * 8);
    }
    __syncthreads();
    bf16x8 af[4], bf[4];
#pragma unroll
    for (int mi = 0; mi < 4; mi++)
      af[mi] = *(const bf16x8*)&As[(wm + mi * 16 + (lane & 15)) * 32 + ((lane >> 4) << 3)];
#pragma unroll
    for (int ni = 0; ni < 4; ni++)
      bf[ni] = *(const bf16x8*)&Bs[(wn + ni * 16 + (lane & 15)) * 32 + ((lane >> 4) << 3)];
#pragma unroll
    for (int mi = 0; mi < 4; mi++)
#pragma unroll
      for (int ni = 0; ni < 4; ni++)
        acc[mi][ni] = __builtin_amdgcn_mfma_f32_16x16x32_bf16(af[mi], bf[ni], acc[mi][ni], 0, 0, 0);
  }

#pragma unroll
  for (int mi = 0; mi < 4; mi++) {
    int g = m0 + wm + mi * 16 + ((lane >> 4) << 2);
#pragma unroll
    for (int ni = 0; ni < 4; ni++) {
      int n = n0 + wn + ni * 16 + (lane & 15);
      int s = n >> 5, b = n & 31;
      ushort4 o = { f2bf(acc[mi][ni][0]), f2bf(acc[mi][ni][1]),
                    f2bf(acc[mi][ni][2]), f2bf(acc[mi][ni][3]) };
      *(ushort4*)(xg + ((size_t)(s * 6 + lg)) * (SB * HD) + (size_t)b * HD + g) = o;
    }
  }
}

// ---------------- phase 2: recurrence ----------------
// A-frag from swizzled LDS weights: row = lane&15, k = k0 + (lane>>4)*8
__device__ __forceinline__ bf16x8 afrag(const short* wlds, int gate, int lane, int k) {
  int r = lane & 15;
  int kk = k + ((lane >> 4) << 3);
  int ck = (kk >> 3) ^ (r & 7);
  return *(const bf16x8*)&wlds[gate * 16384 + r * HD + (ck << 3)];
}

// release-publish to NREP replicas: data stores, vmcnt(0), lane0 flags
__device__ __forceinline__ void publish(unsigned long long* dst0, const f32x4 vals,
                                        unsigned* flag0, unsigned tag, int lane) {
  ushort4 o = { f2bf(vals[0]), f2bf(vals[1]), f2bf(vals[2]), f2bf(vals[3]) };
  unsigned long long q; __builtin_memcpy(&q, &o, 8);
#pragma unroll
  for (int rep = 0; rep < NREP; rep++)
    st_wt(dst0 + (size_t)rep * REP_U64S, q);
  asm volatile("s_waitcnt vmcnt(0)" ::: "memory");   // ALL replicas visible
  if (lane == 0) {
#pragma unroll
    for (int rep = 0; rep < NREP; rep++)
      st_flag(flag0 + (size_t)rep * FLG_WORDS_REP, tag);
  }
}

// acquire: every lane polls one producer flag (in this WG's replica)
__device__ __forceinline__ void flag_wait64(const unsigned* fgrp, int lane, unsigned tag) {
  bool ok;
  do { ok = (ld_flag(&fgrp[lane * 16]) >= tag); } while (!__all(ok));
}

// bulk-load this lane's 2KB payload as 32 wide LLC-coherent plain loads
__device__ __forceinline__ void stage_wide(const unsigned long long* p, u32x4* vv) {
#pragma unroll
  for (int kk = 0; kk < 32; kk++) {
    asm volatile("global_load_dwordx4 %0, %1, off sc0 sc1"
                 : "=v"(vv[kk]) : "v"(p + kk * 8) : "memory");
  }
  asm volatile("s_waitcnt vmcnt(0)" ::: "memory");
  __builtin_amdgcn_sched_barrier(0);
}

__global__ __launch_bounds__(64, 1) void gru_rec(
    const float* __restrict__ h0,
    const float* __restrict__ Uz, const float* __restrict__ Ur, const float* __restrict__ Uh,
    const float* __restrict__ bz, const float* __restrict__ br, const float* __restrict__ bh,
    const unsigned short* __restrict__ xg,
    unsigned long long* __restrict__ hbuf,
    unsigned long long* __restrict__ rbuf,
    unsigned* __restrict__ hflg,
    unsigned* __restrict__ rflg,
    float* __restrict__ out) {
  __shared__ short wlds[3 * 16 * HD];   // 96 KB bf16 U-slices (1 WG/CU)

  const int wg = blockIdx.x;            // 256 WGs, one wave each
  const int l = wg >> 7;
  const int gs = wg & 63;
  const int g0 = gs * 16;
  const int b0 = ((wg >> 6) & 1) * 16;
  const int grp = wg >> 6;              // (l, b-half) group 0..3
  const int lane = threadIdx.x;
  const int col = lane & 15;
  const int sub = lane >> 4;
  const int rb = sub << 2;
  const int rep = gs & 7;               // this WG's read replica

  // ---- load U slices into LDS (bf16, XOR-swizzled 8-elem chunks) ----
  const float* Us[3] = { Uz, Ur, Uh };
#pragma unroll
  for (int gate = 0; gate < 3; gate++) {
    const float* U = Us[gate] + (size_t)l * HD * HD + (size_t)g0 * HD;
    for (int it = 0; it < 32; it++) {
      int chunk = it * 64 + lane;       // 2048 chunks of 8 elems
      int r = chunk >> 7;
      int ck = chunk & 127;
      const float* src = U + (size_t)r * HD + ck * 8;
      float4 a = *(const float4*)src;
      float4 bq = *(const float4*)(src + 4);
      bf16x8 o;
      o[0] = (short)f2bf(a.x); o[1] = (short)f2bf(a.y);
      o[2] = (short)f2bf(a.z); o[3] = (short)f2bf(a.w);
      o[4] = (short)f2bf(bq.x); o[5] = (short)f2bf(bq.y);
      o[6] = (short)f2bf(bq.z); o[7] = (short)f2bf(bq.w);
      int sck = ck ^ (r & 7);
      *(bf16x8*)&wlds[gate * 16384 + r * HD + sck * 8] = o;
    }
  }
  asm volatile("s_waitcnt lgkmcnt(0)" ::: "memory");  // single wave: LDS ready

  f32x4 vbz = *(const f32x4*)(bz + l * HD + g0 + rb);
  f32x4 vbr = *(const f32x4*)(br + l * HD + g0 + rb);
  f32x4 vbh = *(const f32x4*)(bh + l * HD + g0 + rb);

  const int brow = l * SB + b0 + col;                 // [L*B] row index
  f32x4 hreg = *(const f32x4*)(h0 + (size_t)brow * HD + g0 + rb);

  // replica-0 producer targets (publish adds rep*REP_U64S / rep*FLG_WORDS_REP)
  unsigned long long* hdst = hbuf + ((size_t)brow << 8) + ((g0 + rb) >> 2);
  unsigned long long* rdst = rbuf + ((size_t)brow << 8) + ((g0 + rb) >> 2);
  unsigned* hflag0 = hflg + (grp * 64 + gs) * 16;
  unsigned* rflag0 = rflg + (grp * 64 + gs) * 16;
  // this WG's read replica bases
  const unsigned long long* hp = hbuf + (size_t)rep * REP_U64S + ((size_t)brow << 8) + sub * 2;
  const unsigned long long* rp = rbuf + (size_t)rep * REP_U64S + ((size_t)brow << 8) + sub * 2;
  const unsigned* hf_g = hflg + (size_t)rep * FLG_WORDS_REP + grp * 64 * 16;
  const unsigned* rf_g = rflg + (size_t)rep * FLG_WORDS_REP + grp * 64 * 16;

  publish(hdst, hreg, hflag0, 1u, lane);

  // xg current-step values, prefetched one step ahead
  size_t xb0 = ((size_t)l * 3) * (SB * HD) + (size_t)(b0 + col) * HD + g0 + rb;
  uint2 xzc = *(const uint2*)(xg + xb0);
  uint2 xrc = *(const uint2*)(xg + xb0 + SB * HD);
  uint2 xhc = *(const uint2*)(xg + xb0 + 2 * SB * HD);
  uint2 xzn, xrn, xhn;

  u32x4 vv[32];

  for (int s = 0; s < SEQ; s++) {
    const unsigned tag = (unsigned)(s + 1);

    // ---- phase A: z, r (full K=1024 in this wave) ----
    flag_wait64(hf_g, lane, tag);
    stage_wide(hp, vv);
    f32x4 az0 = {0,0,0,0}, az1 = {0,0,0,0}, ar0 = {0,0,0,0}, ar1 = {0,0,0,0};
#pragma unroll
    for (int kk = 0; kk < 32; kk++) {
      union { u32x4 w; bf16x8 b; } u;
      u.w = vv[kk];
      bf16x8 wz = afrag(wlds, 0, lane, kk * 32);
      bf16x8 wr = afrag(wlds, 1, lane, kk * 32);
      if (kk & 1) {
        az1 = __builtin_amdgcn_mfma_f32_16x16x32_bf16(wz, u.b, az1, 0, 0, 0);
        ar1 = __builtin_amdgcn_mfma_f32_16x16x32_bf16(wr, u.b, ar1, 0, 0, 0);
      } else {
        az0 = __builtin_amdgcn_mfma_f32_16x16x32_bf16(wz, u.b, az0, 0, 0, 0);
        ar0 = __builtin_amdgcn_mfma_f32_16x16x32_bf16(wr, u.b, ar0, 0, 0, 0);
      }
    }
    f32x4 accz = az0 + az1, accr = ar0 + ar1;
    f32x4 xzf = unpack4(xzc), xrf = unpack4(xrc);
    f32x4 z, rh;
#pragma unroll
    for (int j = 0; j < 4; j++) {
      float za = xzf[j] + vbz[j] + accz[j];
      float ra = xrf[j] + vbr[j] + accr[j];
      z[j] = 1.f / (1.f + __expf(-za));
      rh[j] = (1.f / (1.f + __expf(-ra))) * hreg[j];
    }
    publish(rdst, rh, rflag0, tag, lane);

    // prefetch next step's xg (overlaps phase-B exchange latency)
    {
      int sn = (s + 1 < SEQ) ? s + 1 : s;
      size_t xbn = ((size_t)sn * 6 + l * 3) * (SB * HD) + (size_t)(b0 + col) * HD + g0 + rb;
      xzn = *(const uint2*)(xg + xbn);
      xrn = *(const uint2*)(xg + xbn + SB * HD);
      xhn = *(const uint2*)(xg + xbn + 2 * SB * HD);
    }

    // ---- phase B: hh, h update ----
    flag_wait64(rf_g, lane, tag);
    stage_wide(rp, vv);
    f32x4 ah0 = {0,0,0,0}, ah1 = {0,0,0,0};
#pragma unroll
    for (int kk = 0; kk < 32; kk++) {
      union { u32x4 w; bf16x8 b; } u;
      u.w = vv[kk];
      bf16x8 wh = afrag(wlds, 2, lane, kk * 32);
      if (kk & 1) ah1 = __builtin_amdgcn_mfma_f32_16x16x32_bf16(wh, u.b, ah1, 0, 0, 0);
      else        ah0 = __builtin_amdgcn_mfma_f32_16x16x32_bf16(wh, u.b, ah0, 0, 0, 0);
    }
    f32x4 acch = ah0 + ah1;
    f32x4 xhf = unpack4(xhc);
#pragma unroll
    for (int j = 0; j < 4; j++) {
      float ha = xhf[j] + vbh[j] + acch[j];
      float e = __expf(2.f * ha);                    // tanh via exp
      float hh = 1.f - 2.f / (e + 1.f);
      hreg[j] = (1.f - z[j]) * hreg[j] + z[j] * hh;
    }
    publish(hdst, hreg, hflag0, tag + 1, lane);

    if (l == 1)      // output stream is LAST layer only
      *(f32x4*)(out + (size_t)s * (SB * HD) + (size_t)(b0 + col) * HD + g0 + rb) = hreg;
    if (s == SEQ - 1)
      *(f32x4*)(out + (size_t)SEQ * SB * HD + (size_t)brow * HD + g0 + rb) = hreg;

    xzc = xzn; xrc = xrn; xhc = xhn;
  }
}

extern "C" void kernel_launch(void* const* d_in, const int* in_sizes, int n_in,
                              void* d_out, int out_size, void* d_ws, size_t ws_size,
                              hipStream_t stream) {
  const float* x  = (const float*)d_in[0];
  const float* h0 = (const float*)d_in[1];
  const float* Wz = (const float*)d_in[2];
  const float* Wr = (const float*)d_in[3];
  const float* Wh = (const float*)d_in[4];
  const float* Uz = (const float*)d_in[5];
  const float* Ur = (const float*)d_in[6];
  const float* Uh = (const float*)d_in[7];
  const float* bz = (const float*)d_in[8];
  const float* br = (const float*)d_in[9];
  const float* bh = (const float*)d_in[10];

  char* ws = (char*)d_ws;
  unsigned short* xg  = (unsigned short*)(ws + XG_OFF);
  unsigned short* xbf = (unsigned short*)(ws + XBF_OFF);
  unsigned short* wbf = (unsigned short*)(ws + WBF_OFF);

  // clear flags (replay safety; data untagged, gated by flags): hflg+rflg
  hipMemsetAsync(ws + HFLG_OFF, 0, FLG_BYTES * 2, stream);

  cvt_f32_bf16<<<1024, 256, 0, stream>>>(x, xbf, (int)(XBF_ELEMS / 4));
  const float* Wsrc[3] = { Wz, Wr, Wh };
  for (int gate = 0; gate < 3; gate++)
    for (int l = 0; l < 2; l++)
      cvt_f32_bf16<<<512, 256, 0, stream>>>(Wsrc[gate] + (size_t)l * HD * HD,
                                            wbf + ((size_t)(l * 3 + gate)) * HD * HD,
                                            HD * HD / 4);

  gemm_xg<<<dim3(128, 8, 6), 256, 0, stream>>>(wbf, xbf, xg);

  gru_rec<<<256, 64, 0, stream>>>(h0, Uz, Ur, Uh, bz, br, bh, xg,
                                  (unsigned long long*)(ws + HBUF_OFF),
                                  (unsigned long long*)(ws + RBUF_OFF),
                                  (unsigned*)(ws + HFLG_OFF),
                                  (unsigned*)(ws + RFLG_OFF),
                                  (float*)d_out);
}